// Round 2
// baseline (808.393 us; speedup 1.0000x reference)
//
#include <hip/hip_runtime.h>

// B=4, T=2048, C=1024, V=50257
// loss = mean_i [ log(sum_v exp(x_i.W_v + b_v)) - (x_i.W_{y_i} + b_{y_i}) ]
// R6: 256x256 LDS-staged fp8-MX GEMM (8-phase-template structure, T2+T3+T4+T5).
//  - packed fragments staged to LDS via global_load_lds (16B), double-buffered:
//    unique 64KB/iter shared by 8 waves (was 192KB/CU of duplicate global reads)
//  - stage issued at iter start, vmcnt(0) drained at iter end (~1100 cyc cover)
//  - chunk swizzle c^=(c>>3)&7 baked into pack -> conflict-free ds_read_b128
//  - raw s_barrier phase structure + s_setprio(1) around MFMA cluster
//  - bias block staged to LDS once (epilogue had 128 broadcast loads/thread)

#define M_TOT 8192
#define K_TOT 1024
#define V_TOT 50257
#define NVB   197                // vocab blocks of 256
#define NPAD  (NVB * 256)        // 50432
#define PSTRIDE (NVB * 2)        // 394 partials per batch row
#define KB    (K_TOT / 64)       // 16 K-steps of 64
#define GSTRIDE ((long)KB * 64 * 32)   // bytes per packed 32-row group (32KB)

typedef __attribute__((ext_vector_type(8)))  int   int8v;
typedef __attribute__((ext_vector_type(16))) float floatx16;

__device__ __forceinline__ int f4_to_fp8x4(float4 v) {
  int r = __builtin_amdgcn_cvt_pk_fp8_f32(v.x, v.y, 0, false);
  r = __builtin_amdgcn_cvt_pk_fp8_f32(v.z, v.w, r, true);
  return r;
}

// Packed layout (R3-verified base + R6 chunk swizzle): for 32-row group g,
// K-step kb, MFMA lane l = h*32 + r, k-byte b in 0..31:
//   logical chunk c = l*2 + (b>>4)  (128 16B chunks per 2KB span)
//   physical chunk sc = c ^ ((c>>3)&7)   (involution; read side uses same map)
//   p[(g*KB+kb)*2048 + sc*16 + (b&15)] = fp8(src[g*32 + r][kb*64 + h*32 + b])
// Thread i: row r=i>>3, seg=i&7 — reads 2x float4 (coalesced), writes one 8B
// piece of chunk c = (h*32+r)*2 + ((seg>>1)&1) at half (seg&1).
__global__ __launch_bounds__(256) void pack_kernel(
    const float* __restrict__ src, char* __restrict__ dst, int nrows) {
  const int kb = blockIdx.x, g = blockIdx.y;
  const int i = threadIdx.x;
  const int r = i >> 3, seg = i & 7;
  const int srow = g * 32 + r;
  int lo = 0, hi = 0;
  if (srow < nrows) {
    const float4* s = (const float4*)(src + (long)srow * K_TOT + kb * 64 + seg * 8);
    lo = f4_to_fp8x4(s[0]);
    hi = f4_to_fp8x4(s[1]);
  }
  const int h = seg >> 2;
  const int c = (h * 32 + r) * 2 + ((seg >> 1) & 1);
  const int sc = c ^ ((c >> 3) & 7);
  char* d = dst + ((long)(g * KB + kb) * 2048 + sc * 16 + (seg & 1) * 8);
  *(int2*)d = make_int2(lo, hi);
}

#define GLOAD16(gp, lp)                                              \
  __builtin_amdgcn_global_load_lds(                                  \
      (const __attribute__((address_space(1))) void*)(gp),           \
      (__attribute__((address_space(3))) void*)(lp), 16, 0, 0)

__device__ __forceinline__ int8v read_frag(const char* base, int o0, int o1) {
  int4 lo = *(const int4*)(base + o0);
  int4 hi = *(const int4*)(base + o1);
  int8v r;
  r[0] = lo.x; r[1] = lo.y; r[2] = lo.z; r[3] = lo.w;
  r[4] = hi.x; r[5] = hi.y; r[6] = hi.z; r[7] = hi.w;
  return r;
}

// Block tile: 256 vocab x 256 batch, 8 waves (wv in 0..1 -> 128 vocab rows,
// wb in 0..3 -> 64 batch cols), per-wave 4x2 mfma_scale_f32_32x32x64 (unit
// scales = plain fp8). K loop: 8 iters x BK=128 (2 K-steps), LDS dbuf.
__global__ __launch_bounds__(512, 2) void gemm_lse_kernel(
    const char* __restrict__ pW, const char* __restrict__ pX,
    const float* __restrict__ bias, float* __restrict__ psum) {
  __shared__ char ldsA[2][32768];    // [buf][group 0..7][kstep 0..1][2KB]
  __shared__ char ldsB[2][32768];
  __shared__ float ldsbias[256];

  const int tid  = threadIdx.x;
  const int wid  = tid >> 6;
  const int lane = tid & 63;
  const int wv   = wid >> 2;           // vocab half (128 rows)
  const int wb   = wid & 3;            // batch quarter (64 cols)
  const int mblk = blockIdx.x;         // 0..31
  const int vblk = blockIdx.y;         // 0..196

  // per-lane swizzled chunk offsets within a 2KB fragment span
  const int c0 = lane * 2, c1 = c0 + 1;
  const int off0 = (c0 ^ ((c0 >> 3) & 7)) * 16;
  const int off1 = (c1 ^ ((c1 >> 3) & 7)) * 16;

  // wave wid stages A-group wid and B-group wid; 4KB (= ksteps 2t,2t+1) each.
  const char* srcA = pW + (long)(vblk * 8 + wid) * GSTRIDE + lane * 16;
  const char* srcB = pX + (long)(mblk * 8 + wid) * GSTRIDE + lane * 16;

  auto stage = [&](int buf, int t) {
#pragma unroll
    for (int i = 0; i < 4; ++i) {
      GLOAD16(srcA + (long)t * 4096 + i * 1024, ldsA[buf] + wid * 4096 + i * 1024);
      GLOAD16(srcB + (long)t * 4096 + i * 1024, ldsB[buf] + wid * 4096 + i * 1024);
    }
  };

  floatx16 acc[4][2] = {};

  auto do_phase = [&](int cur, int s) {
    int8v a[4], b[2];
#pragma unroll
    for (int tn = 0; tn < 2; ++tn)
      b[tn] = read_frag(ldsB[cur] + ((wb * 2 + tn) * 2 + s) * 2048, off0, off1);
#pragma unroll
    for (int tv = 0; tv < 4; ++tv)
      a[tv] = read_frag(ldsA[cur] + ((wv * 4 + tv) * 2 + s) * 2048, off0, off1);
    asm volatile("" ::: "memory");
    __builtin_amdgcn_s_barrier();      // reads in flight across barrier
    asm volatile("" ::: "memory");
    __builtin_amdgcn_s_setprio(1);
#pragma unroll
    for (int tv = 0; tv < 4; ++tv)
#pragma unroll
      for (int tn = 0; tn < 2; ++tn)
        acc[tv][tn] = __builtin_amdgcn_mfma_scale_f32_32x32x64_f8f6f4(
            a[tv], b[tn], acc[tv][tn], 0, 0, 0, 0x7F7F7F7F, 0, 0x7F7F7F7F);
    __builtin_amdgcn_s_setprio(0);
  };

  // prologue: stage iter 0 + bias block; full drain via __syncthreads
  stage(0, 0);
  if (tid < 256) {
    int v = vblk * 256 + tid;
    ldsbias[tid] = (v < V_TOT) ? bias[v] : -1e30f;   // exp -> 0 for pad rows
  }
  __syncthreads();

  for (int t = 0; t < 8; ++t) {
    const int cur = t & 1, nxt = cur ^ 1;
    // phase 0: issue next-iter stage early (safe: buf[nxt] reads finished
    // before the iter-(t-1) ending barrier), compute kstep 0
    if (t < 7) stage(nxt, t + 1);
    do_phase(cur, 0);
    asm volatile("" ::: "memory");
    __builtin_amdgcn_s_barrier();
    asm volatile("" ::: "memory");
    // phase 1: compute kstep 1, then drain stages (issued ~2 phases ago ->
    // counted-vmcnt effect: wait is ~free) and cross iter boundary
    do_phase(cur, 1);
    asm volatile("s_waitcnt vmcnt(0)" ::: "memory");
    __builtin_amdgcn_s_barrier();
    asm volatile("" ::: "memory");
  }

  // Epilogue. C layout (verified R2/R3): col(batch) = l32,
  // row(vocab within 32-group) = (reg&3) + 8*(reg>>2) + 4*half.
  const int half = lane >> 5, l32 = lane & 31;
  const int bbase = wv * 128 + 4 * half;
  float s0 = 0.0f, s1 = 0.0f;
#pragma unroll
  for (int tv = 0; tv < 4; ++tv) {
#pragma unroll
    for (int reg = 0; reg < 16; ++reg) {
      float bv = ldsbias[bbase + tv * 32 + (reg & 3) + 8 * (reg >> 2)];
      s0 += __expf(acc[tv][0][reg] + bv);
      s1 += __expf(acc[tv][1][reg] + bv);
    }
  }
  s0 += __shfl_xor(s0, 32, 64);
  s1 += __shfl_xor(s1, 32, 64);
  if (half == 0) {
    int m = mblk * 256 + wb * 64 + l32;
    long base = (long)m * PSTRIDE + vblk * 2 + wv;
    psum[base] = s0;                                // tn = 0
    psum[base + (long)32 * PSTRIDE] = s1;           // tn = 1 (m + 32)
  }
}

// One wave per batch row: sum 394 partials -> log; exact fp32 label logit.
__global__ __launch_bounds__(256) void finalize_kernel(
    const float* __restrict__ psum, const float* __restrict__ x,
    const float* __restrict__ W, const float* __restrict__ b,
    const int* __restrict__ y, float* __restrict__ loss) {
  const int wave = threadIdx.x >> 6;
  const int lane = threadIdx.x & 63;
  const int r = blockIdx.x * 4 + wave;

  const float* ps = psum + (long)r * PSTRIDE;
  float s = 0.0f;
  for (int j = lane; j < PSTRIDE; j += 64) s += ps[j];
#pragma unroll
  for (int o = 1; o < 64; o <<= 1) s += __shfl_xor(s, o, 64);

  int label = y[r];
  const float4* xr = (const float4*)(x + (long)r * K_TOT);
  const float4* wr = (const float4*)(W + (long)label * K_TOT);
  float d = 0.0f;
  for (int j = lane; j < K_TOT / 4; j += 64) {
    float4 a = xr[j], w = wr[j];
    d += a.x * w.x + a.y * w.y + a.z * w.z + a.w * w.w;
  }
#pragma unroll
  for (int o = 1; o < 64; o <<= 1) d += __shfl_xor(d, o, 64);

  if (lane == 0) loss[r] = logf(s) - d - b[label];
}

// Single block: deterministic mean of 8192 per-row losses.
__global__ __launch_bounds__(256) void reduce_kernel(
    const float* __restrict__ loss, float* __restrict__ out) {
  const int tid = threadIdx.x;
  float s = 0.0f;
  for (int j = tid; j < M_TOT; j += 256) s += loss[j];
#pragma unroll
  for (int o = 1; o < 64; o <<= 1) s += __shfl_xor(s, o, 64);
  __shared__ float wsum[4];
  if ((tid & 63) == 0) wsum[tid >> 6] = s;
  __syncthreads();
  if (tid == 0)
    out[0] = (wsum[0] + wsum[1] + wsum[2] + wsum[3]) * (1.0f / (float)M_TOT);
}

extern "C" void kernel_launch(void* const* d_in, const int* in_sizes, int n_in,
                              void* d_out, int out_size, void* d_ws, size_t ws_size,
                              hipStream_t stream) {
  (void)in_sizes; (void)n_in; (void)out_size; (void)ws_size;
  const float* x = (const float*)d_in[0];
  const int*   y = (const int*)d_in[1];
  const float* W = (const float*)d_in[2];
  const float* b = (const float*)d_in[3];
  float* out = (float*)d_out;

  char* ws = (char*)d_ws;
  const size_t PX_BYTES = (size_t)M_TOT * K_TOT;            // 8.4 MB
  const size_t PW_BYTES = (size_t)NPAD * K_TOT;             // 51.6 MB
  const size_t PS_BYTES = (size_t)M_TOT * PSTRIDE * 4;      // 12.9 MB
  char*  pX   = ws;
  char*  pW   = ws + PX_BYTES;
  float* psum = (float*)(ws + PX_BYTES + PW_BYTES);
  float* loss = (float*)(ws + PX_BYTES + PW_BYTES + PS_BYTES);

  pack_kernel<<<dim3(KB, M_TOT / 32), 256, 0, stream>>>(x, pX, M_TOT);
  pack_kernel<<<dim3(KB, NPAD / 32), 256, 0, stream>>>(W, pW, V_TOT);
  gemm_lse_kernel<<<dim3(M_TOT / 256, NVB), 512, 0, stream>>>(pW, pX, b, psum);
  finalize_kernel<<<M_TOT / 4, 256, 0, stream>>>(psum, x, W, b, y, loss);
  reduce_kernel<<<1, 256, 0, stream>>>(loss, out);
}